// Round 8
// baseline (2235.364 us; speedup 1.0000x reference)
//
#include <hip/hip_runtime.h>
#include <hip/hip_bf16.h>

// CTRNN on MI355X — single fused kernel.
//   out layout (fp32): output[512][128][1024] | hidden[128][1024] | ip[512][128][1024]
// Blocks 0..127    : persistent recurrent blocks (8 batch-tiles x 16 H-tiles),
//                    W_hh slice in VGPRs, K-split across 4 waves, h exchanged via
//                    depth-2 sc0+sc1 ring + per-WAVE 16B-padded flags. The per-t
//                    ip-progress check is folded into the h-flag poll (lane 16+).
// Blocks 128..+16383: ip tiles (64x64, K=512), W_in converted inline, epilogue
//                    TRANSPOSED through LDS -> contiguous dwordx4 sc0+sc1 stores
//                    (write-through so rec's reads are fresh), per-t counter.
// 84KB static LDS forces 1 block/CU: ip blocks never co-tenant rec CUs.

typedef __attribute__((ext_vector_type(8))) short short8;
typedef __attribute__((ext_vector_type(4))) float f32x4;

#define S_LEN 512
#define BATCH 128
#define IN_DIM 512
#define HID 1024
#define NREC 128
#define IP_TILES 16384   // (65536/64) M-tiles * (1024/64) N-tiles

__device__ __forceinline__ ushort f2bf(float f) {
    __hip_bfloat16 h = __float2bfloat16(f);
    return *reinterpret_cast<ushort*>(&h);
}

__global__ __launch_bounds__(256, 1) void ctrnn_fused(
        const float* __restrict__ x, const float* __restrict__ W_in,
        const float* __restrict__ b_in, const float* __restrict__ whh,
        const float* __restrict__ b_hh, float* __restrict__ out,
        float* __restrict__ hidden, float* __restrict__ ip,
        ushort* __restrict__ hbuf, int* __restrict__ flags,
        int* __restrict__ flags_ip) {
    __shared__ __align__(16) char lds_raw[84 * 1024];
    const int tid  = threadIdx.x;
    const int lane = tid & 63;
    const int w    = tid >> 6;

    if (blockIdx.x >= NREC) {
        // ======================= ip tile =======================
        ushort* As = (ushort*)lds_raw;
        ushort* Bs = (ushort*)(lds_raw + 4096);
        float*  T  = (float*)(lds_raw + 8192);     // [64][68] transpose tile
        const int bid = blockIdx.x - NREC;
        const int mt  = bid >> 4;          // ascending t with blockIdx
        const int nt  = bid & 15;
        const long Mbase = (long)mt * 64;
        const int  Nbase = nt * 64;
        const int sr = tid >> 2;
        const int sk = (tid & 3) * 8;

        f32x4 acc0 = {0,0,0,0}, acc1 = {0,0,0,0}, acc2 = {0,0,0,0}, acc3 = {0,0,0,0};
        const int ar   = w * 16 + (lane & 15);
        const int kb   = ((lane >> 4) * 8) * 2;
        const int aoff = (ar * 64 + kb) ^ ((ar & 7) << 4);
        const int boff = ((lane & 15) * 64 + kb) ^ (((lane & 15) & 7) << 4);
        const int soff = (sr * 64 + sk * 2) ^ ((sr & 7) << 4);

        for (int kc = 0; kc < IN_DIM; kc += 32) {
            const float* apg = x + (Mbase + sr) * IN_DIM + kc + sk;
            f32x4 av0 = *(const f32x4*)apg;
            f32x4 av1 = *(const f32x4*)(apg + 4);
            const float* wpg = W_in + (size_t)(Nbase + sr) * IN_DIM + kc + sk;
            f32x4 bv0 = *(const f32x4*)wpg;
            f32x4 bv1 = *(const f32x4*)(wpg + 4);
            short8 av, bv;
#pragma unroll
            for (int j = 0; j < 4; ++j) {
                av[j]     = (short)f2bf(av0[j]);
                av[4 + j] = (short)f2bf(av1[j]);
                bv[j]     = (short)f2bf(bv0[j]);
                bv[4 + j] = (short)f2bf(bv1[j]);
            }
            __syncthreads();
            *(short8*)((char*)As + soff) = av;
            *(short8*)((char*)Bs + soff) = bv;
            __syncthreads();

            short8 a  = *(const short8*)((char*)As + aoff);
            short8 b0 = *(const short8*)((char*)Bs + boff);
            short8 b1 = *(const short8*)((char*)Bs + boff + 1024);
            short8 b2 = *(const short8*)((char*)Bs + boff + 2048);
            short8 b3 = *(const short8*)((char*)Bs + boff + 3072);
            acc0 = __builtin_amdgcn_mfma_f32_16x16x32_bf16(a, b0, acc0, 0, 0, 0);
            acc1 = __builtin_amdgcn_mfma_f32_16x16x32_bf16(a, b1, acc1, 0, 0, 0);
            acc2 = __builtin_amdgcn_mfma_f32_16x16x32_bf16(a, b2, acc2, 0, 0, 0);
            acc3 = __builtin_amdgcn_mfma_f32_16x16x32_bf16(a, b3, acc3, 0, 0, 0);
        }

        // epilogue: C-frags -> LDS transpose -> contiguous dwordx4 stores
        const int nl   = lane & 15;
        const int mrow = w * 16 + (lane >> 4) * 4;
        const float bi0 = b_in[Nbase + nl];
        const float bi1 = b_in[Nbase + 16 + nl];
        const float bi2 = b_in[Nbase + 32 + nl];
        const float bi3 = b_in[Nbase + 48 + nl];
        __syncthreads();
#pragma unroll
        for (int j = 0; j < 4; ++j) {
            float* Tr = T + (mrow + j) * 68;
            Tr[nl]      = acc0[j] + bi0;
            Tr[16 + nl] = acc1[j] + bi1;
            Tr[32 + nl] = acc2[j] + bi2;
            Tr[48 + nl] = acc3[j] + bi3;
        }
        __syncthreads();
        const int rr = tid >> 2, cc = (tid & 3) * 16;
        float* op = ip + (Mbase + rr) * HID + Nbase + cc;
#pragma unroll
        for (int q = 0; q < 4; ++q) {
            f32x4 v = *(const f32x4*)(T + rr * 68 + cc + q * 4);
            asm volatile("global_store_dwordx4 %0, %1, off sc0 sc1"
                         :: "v"(op + q * 4), "v"(v) : "memory");
        }
        asm volatile("s_waitcnt vmcnt(0)" ::: "memory");
        __syncthreads();
        if (tid == 0) atomicAdd(&flags_ip[mt >> 1], 1);   // 32 tiles per t
        return;
    }

    // ======================= recurrent block =======================
    float* P = (float*)lds_raw;   // [4][16][68] K-partials, padded
    const int bi = blockIdx.x & 7;
    const int ni = blockIdx.x >> 3;
    const int arow = lane & 15;
    const int kgrp = (lane >> 4) * 8;

    // W_hh fragments: wf[g][kk] = W[ni*64+g*16+arow][w*256 + kk*32 + kgrp + 0..7]
    short8 wf[4][8];
#pragma unroll
    for (int g = 0; g < 4; ++g)
#pragma unroll
        for (int kk = 0; kk < 8; ++kk) {
            const float* wp = whh + (size_t)(ni * 64 + g * 16 + arow) * HID
                              + w * 256 + kk * 32 + kgrp;
            f32x4 w0 = *(const f32x4*)wp;
            f32x4 w1 = *(const f32x4*)(wp + 4);
            short8 f;
#pragma unroll
            for (int j = 0; j < 4; ++j) {
                f[j]     = (short)f2bf(w0[j]);
                f[4 + j] = (short)f2bf(w1[j]);
            }
            wf[g][kk] = f;
        }

    const int eb = tid >> 4;
    const int n0 = (tid & 15) * 4;
    const f32x4 bias4 = *(const f32x4*)&b_hh[ni * 64 + n0];
    const float* xsrc = ip + (size_t)(bi * 16 + eb) * HID + ni * 64 + n0;
    f32x4 hprev = {0, 0, 0, 0};
    f32x4 xtv;

    // ---- t=0 gate: wait for ip[0], then load first xt (bypass, fresh) ----
    {
        const int* fip = flags_ip;
        long spin = 0;
        for (;;) {
            int v;
            asm volatile("global_load_dword %0, %1, off sc0 sc1\n\ts_waitcnt vmcnt(0)"
                         : "=v"(v) : "v"(fip) : "memory");
            if (__all(v >= 32)) break;
            if (++spin > (1L << 22)) break;
        }
        asm volatile("global_load_dwordx4 %0, %1, off sc0 sc1\n\ts_waitcnt vmcnt(0)"
                     : "=v"(xtv) : "v"(xsrc) : "memory");
    }

    for (int t = 0; t < S_LEN; ++t) {
        f32x4 acc = {0, 0, 0, 0};
        if (t > 0) {
            // ---- combined poll: lanes 0-15 h-flags(t-1); lanes 16+ ip counter(t) ----
            {
                const int* pl = (lane < 16)
                    ? flags + (((size_t)(t - 1) * 8 + bi) * 64 + w * 16 + lane) * 4
                    : flags_ip + t;
                long spin = 0;
                for (;;) {
                    int v;
                    asm volatile("global_load_dword %0, %1, off sc0 sc1\n\ts_waitcnt vmcnt(0)"
                                 : "=v"(v) : "v"(pl) : "memory");
                    int okl = (lane < 16) ? (v != 0) : (v >= 32);
                    if (__all(okl)) break;
                    if (++spin > (1L << 22)) break;
                }
            }

            // ---- load A-frags + this step's xt (latency hides under vmcnt+MFMA) ----
            const ushort* hs = hbuf + (size_t)((t - 1) & 1) * BATCH * HID
                               + (size_t)(bi * 16 + arow) * HID + w * 256 + kgrp;
            short8 af0, af1, af2, af3, af4, af5, af6, af7;
#define LDA(reg, kk)                                                            \
            asm volatile("global_load_dwordx4 %0, %1, off sc0 sc1"              \
                         : "=v"(reg) : "v"(hs + (kk) * 32) : "memory")
            LDA(af0, 0); LDA(af1, 1); LDA(af2, 2); LDA(af3, 3);
            LDA(af4, 4); LDA(af5, 5); LDA(af6, 6); LDA(af7, 7);
#undef LDA
            asm volatile("global_load_dwordx4 %0, %1, off sc0 sc1"
                         : "=v"(xtv) : "v"(xsrc + (size_t)t * BATCH * HID) : "memory");
            asm volatile("s_waitcnt vmcnt(1)" ::: "memory");   // A-frags ready (xt may lag)
            __builtin_amdgcn_sched_barrier(0);

            // ---- 32 MFMAs: 4 n-groups x 8 k-chunks (K-partials) ----
            f32x4 a0 = {0,0,0,0}, a1 = {0,0,0,0}, a2 = {0,0,0,0}, a3 = {0,0,0,0};
#define STEP(afk, kk)                                                               \
            a0 = __builtin_amdgcn_mfma_f32_16x16x32_bf16(afk, wf[0][kk], a0, 0, 0, 0); \
            a1 = __builtin_amdgcn_mfma_f32_16x16x32_bf16(afk, wf[1][kk], a1, 0, 0, 0); \
            a2 = __builtin_amdgcn_mfma_f32_16x16x32_bf16(afk, wf[2][kk], a2, 0, 0, 0); \
            a3 = __builtin_amdgcn_mfma_f32_16x16x32_bf16(afk, wf[3][kk], a3, 0, 0, 0)
            STEP(af0, 0); STEP(af1, 1); STEP(af2, 2); STEP(af3, 3);
            STEP(af4, 4); STEP(af5, 5); STEP(af6, 6); STEP(af7, 7);
#undef STEP

            // ---- write K-partials (C/D map: row=(lane>>4)*4+j, col=arow) ----
#pragma unroll
            for (int j = 0; j < 4; ++j) {
                const int br = (lane >> 4) * 4 + j;
                float* Pr = P + w * 1088 + br * 68;
                Pr[arow]      = a0[j];
                Pr[16 + arow] = a1[j];
                Pr[32 + arow] = a2[j];
                Pr[48 + arow] = a3[j];
            }
            asm volatile("s_waitcnt vmcnt(0)" ::: "memory");   // xt ready
            __syncthreads();

            // ---- reduce 4 wave-partials for (eb, n0..n0+3) ----
            f32x4 r0 = *(const f32x4*)(P + 0 * 1088 + eb * 68 + n0);
            f32x4 r1 = *(const f32x4*)(P + 1 * 1088 + eb * 68 + n0);
            f32x4 r2 = *(const f32x4*)(P + 2 * 1088 + eb * 68 + n0);
            f32x4 r3 = *(const f32x4*)(P + 3 * 1088 + eb * 68 + n0);
            acc = (r0 + r1) + (r2 + r3);
        }

        // ---- epilogue: hnew = relu(xt + Wh + b); h = 0.8h + 0.2hnew ----
        f32x4 hw;
#pragma unroll
        for (int j = 0; j < 4; ++j) {
            float hn = xtv[j] + acc[j] + bias4[j];
            hn       = hn > 0.0f ? hn : 0.0f;
            hw[j]    = hprev[j] * 0.8f + 0.2f * hn;
        }
        hprev = hw;

        // ---- publish 8B bf16 -> per-wave drain -> per-wave flag (no barrier) ----
        uint2 pk;
        pk.x = (uint)f2bf(hw[0]) | ((uint)f2bf(hw[1]) << 16);
        pk.y = (uint)f2bf(hw[2]) | ((uint)f2bf(hw[3]) << 16);
        ushort* hdst = hbuf + (size_t)(t & 1) * BATCH * HID
                       + (size_t)(bi * 16 + eb) * HID + ni * 64 + n0;
        asm volatile("global_store_dwordx2 %0, %1, off sc0 sc1" :: "v"(hdst), "v"(pk) : "memory");
        asm volatile("s_waitcnt vmcnt(0)" ::: "memory");
        if (lane == 0) {
            int one = 1;
            int* fdst = flags + (((size_t)t * 8 + bi) * 64 + ni * 4 + w) * 4;
            asm volatile("global_store_dword %0, %1, off sc0 sc1" :: "v"(fdst), "v"(one) : "memory");
        }

        // ---- off-critical-path: out/hidden stores ----
        float* od = out + (size_t)t * BATCH * HID + (size_t)(bi * 16 + eb) * HID + ni * 64 + n0;
        *(f32x4*)od = hw;
        if (t == S_LEN - 1) {
            float* hd = hidden + (size_t)(bi * 16 + eb) * HID + ni * 64 + n0;
            *(f32x4*)hd = hw;
        }
    }
}

extern "C" void kernel_launch(void* const* d_in, const int* in_sizes, int n_in,
                              void* d_out, int out_size, void* d_ws, size_t ws_size,
                              hipStream_t stream) {
    const float* x    = (const float*)d_in[0];
    const float* W_in = (const float*)d_in[1];
    const float* b_in = (const float*)d_in[2];
    const float* W_hh = (const float*)d_in[3];
    const float* b_hh = (const float*)d_in[4];

    float* out    = (float*)d_out;
    float* hidden = out + (size_t)S_LEN * BATCH * HID;
    float* ip     = hidden + (size_t)BATCH * HID;

    char* ws = (char*)d_ws;
    ushort* hbuf     = (ushort*)ws;                              // 512 KB h ring
    int*    flags_ip = (int*)(ws + 768 * 1024);                  // 2 KB per-t counters
    int*    flags    = (int*)(ws + (size_t)1024 * 1024);         // 4 MB wave flags (16B pad)

    hipMemsetAsync(flags_ip, 0, S_LEN * sizeof(int), stream);
    hipMemsetAsync(flags, 0, (size_t)S_LEN * 8 * 64 * 4 * sizeof(int), stream);
    ctrnn_fused<<<NREC + IP_TILES, 256, 0, stream>>>(x, W_in, b_in, W_hh, b_hh,
                                                     out, hidden, ip, hbuf, flags, flags_ip);
}

// Round 9
// 2127.491 us; speedup vs baseline: 1.0507x; 1.0507x over previous
//
#include <hip/hip_runtime.h>
#include <hip/hip_bf16.h>

// CTRNN on MI355X.
//   out layout (fp32): output[512][128][1024] | hidden[128][1024] | ip[512][128][1024]
// Phase 1: ip = x @ W_in^T + b_in  (bf16 MFMA, W_in converted inline, fp32 out)
// Phase 2: persistent recurrent kernel (R6 structure, proven):
//          128 blocks = 8 batch-tiles x 16 H-tiles; W_hh slice in VGPRs;
//          K-split across 4 waves; h exchanged via depth-2 sc0+sc1 ring +
//          per-BLOCK 16B-padded flags (barrier + tid0, as R6). NEW: rolling
//          2-deep flag poll (halves detect sampling interval; stale reads
//          return 0 -> retry, never false-positive).

typedef __attribute__((ext_vector_type(8))) short short8;
typedef __attribute__((ext_vector_type(4))) float f32x4;

#define S_LEN 512
#define BATCH 128
#define IN_DIM 512
#define HID 1024

__device__ __forceinline__ ushort f2bf(float f) {
    __hip_bfloat16 h = __float2bfloat16(f);
    return *reinterpret_cast<ushort*>(&h);
}

// ---------------- input projection GEMM (inline W_in cvt) ----------------
__global__ __launch_bounds__(256) void ip_gemm(const float* __restrict__ x,
                                               const float* __restrict__ W_in,
                                               const float* __restrict__ b_in,
                                               float* __restrict__ ip) {
    __shared__ __align__(16) ushort As[64 * 32];
    __shared__ __align__(16) ushort Bs[64 * 32];
    const int tid  = threadIdx.x;
    const int lane = tid & 63;
    const int w    = tid >> 6;
    const int mt   = blockIdx.x >> 4;
    const int nt   = blockIdx.x & 15;
    const long Mbase = (long)mt * 64;
    const int  Nbase = nt * 64;

    const int sr = tid >> 2;
    const int sk = (tid & 3) * 8;

    f32x4 acc0 = {0,0,0,0}, acc1 = {0,0,0,0}, acc2 = {0,0,0,0}, acc3 = {0,0,0,0};

    const int ar    = w * 16 + (lane & 15);
    const int kb    = ((lane >> 4) * 8) * 2;
    const int aoff  = (ar * 64 + kb) ^ ((ar & 7) << 4);
    const int boff  = ((lane & 15) * 64 + kb) ^ (((lane & 15) & 7) << 4);
    const int soff  = (sr * 64 + sk * 2) ^ ((sr & 7) << 4);

    for (int kc = 0; kc < IN_DIM; kc += 32) {
        const float* ap = x + (Mbase + sr) * IN_DIM + kc + sk;
        f32x4 av0 = *(const f32x4*)ap;
        f32x4 av1 = *(const f32x4*)(ap + 4);
        const float* wp = W_in + (size_t)(Nbase + sr) * IN_DIM + kc + sk;
        f32x4 bv0 = *(const f32x4*)wp;
        f32x4 bv1 = *(const f32x4*)(wp + 4);
        short8 av, bv;
#pragma unroll
        for (int j = 0; j < 4; ++j) {
            av[j]     = (short)f2bf(av0[j]);
            av[4 + j] = (short)f2bf(av1[j]);
            bv[j]     = (short)f2bf(bv0[j]);
            bv[4 + j] = (short)f2bf(bv1[j]);
        }
        __syncthreads();
        *(short8*)((char*)As + soff) = av;
        *(short8*)((char*)Bs + soff) = bv;
        __syncthreads();

        short8 a  = *(const short8*)((char*)As + aoff);
        short8 b0 = *(const short8*)((char*)Bs + boff);
        short8 b1 = *(const short8*)((char*)Bs + boff + 1024);
        short8 b2 = *(const short8*)((char*)Bs + boff + 2048);
        short8 b3 = *(const short8*)((char*)Bs + boff + 3072);
        acc0 = __builtin_amdgcn_mfma_f32_16x16x32_bf16(a, b0, acc0, 0, 0, 0);
        acc1 = __builtin_amdgcn_mfma_f32_16x16x32_bf16(a, b1, acc1, 0, 0, 0);
        acc2 = __builtin_amdgcn_mfma_f32_16x16x32_bf16(a, b2, acc2, 0, 0, 0);
        acc3 = __builtin_amdgcn_mfma_f32_16x16x32_bf16(a, b3, acc3, 0, 0, 0);
    }

    const int nl   = lane & 15;
    const int mrow = w * 16 + (lane >> 4) * 4;
    const float bi0 = b_in[Nbase + nl];
    const float bi1 = b_in[Nbase + 16 + nl];
    const float bi2 = b_in[Nbase + 32 + nl];
    const float bi3 = b_in[Nbase + 48 + nl];
#pragma unroll
    for (int j = 0; j < 4; ++j) {
        float* op = ip + (Mbase + mrow + j) * HID + Nbase + nl;
        op[0]  = acc0[j] + bi0;
        op[16] = acc1[j] + bi1;
        op[32] = acc2[j] + bi2;
        op[48] = acc3[j] + bi3;
    }
}

// ---------------- persistent recurrent kernel ----------------
// grid = 128 blocks: bi = blockIdx&7 (16 batch rows), ni = blockIdx>>3 (64 H cols).
// flags[((t*8+bi)*64 + ni*4 + w)*4]: wave w of block (bi,ni) published h[t]
// (per-wave publish, no producer barrier — proven in R6).
__global__ __launch_bounds__(256, 1) void ctrnn_rec(const float* __restrict__ whh,
                                                    const float* __restrict__ b_hh,
                                                    const float* __restrict__ ip,
                                                    float* __restrict__ out,
                                                    float* __restrict__ hidden,
                                                    ushort* __restrict__ hbuf,
                                                    int* __restrict__ flags) {
    const int tid  = threadIdx.x;
    const int lane = tid & 63;
    const int w    = tid >> 6;
    const int bi   = blockIdx.x & 7;
    const int ni   = blockIdx.x >> 3;

    __shared__ __align__(16) float P[4][16][68];   // 17.4 KB K-partials (padded)

    const int arow = lane & 15;          // A row = batch row; also W col within group
    const int kgrp = (lane >> 4) * 8;    // k sub-offset within 32-chunk

    // W_hh fragments: wf[g][kk] = W[ni*64+g*16+arow][w*256 + kk*32 + kgrp + 0..7]
    short8 wf[4][8];
#pragma unroll
    for (int g = 0; g < 4; ++g)
#pragma unroll
        for (int kk = 0; kk < 8; ++kk) {
            const float* wp = whh + (size_t)(ni * 64 + g * 16 + arow) * HID
                              + w * 256 + kk * 32 + kgrp;
            f32x4 w0 = *(const f32x4*)wp;
            f32x4 w1 = *(const f32x4*)(wp + 4);
            short8 f;
#pragma unroll
            for (int j = 0; j < 4; ++j) {
                f[j]     = (short)f2bf(w0[j]);
                f[4 + j] = (short)f2bf(w1[j]);
            }
            wf[g][kk] = f;
        }

    const int eb = tid >> 4;
    const int n0 = (tid & 15) * 4;
    const f32x4 bias4 = *(const f32x4*)&b_hh[ni * 64 + n0];
    f32x4 hprev = {0, 0, 0, 0};
    f32x4 xtv   = *(const f32x4*)&ip[(size_t)(bi * 16 + eb) * HID + ni * 64 + n0];

    for (int t = 0; t < S_LEN; ++t) {
        f32x4 acc = {0, 0, 0, 0};
        if (t > 0) {
            // ---- rolling 2-deep poll of 16 producer-wave flags (lanes 0-15) ----
            if (lane < 16) {
                const int* fl = flags + (((size_t)(t - 1) * 8 + bi) * 64 + w * 16 + lane) * 4;
                int v0 = 0, v1 = 0;
                long spin = 0;
                asm volatile("global_load_dword %0, %1, off sc0 sc1"
                             : "=v"(v0) : "v"(fl) : "memory");
                for (;;) {
                    asm volatile("global_load_dword %0, %1, off sc0 sc1"
                                 : "=v"(v1) : "v"(fl) : "memory");
                    asm volatile("s_waitcnt vmcnt(1)" ::: "memory");   // v0 ready
                    if (__all(v0 != 0)) break;
                    asm volatile("global_load_dword %0, %1, off sc0 sc1"
                                 : "=v"(v0) : "v"(fl) : "memory");
                    asm volatile("s_waitcnt vmcnt(1)" ::: "memory");   // v1 ready
                    if (__all(v1 != 0)) break;
                    if (++spin > (1L << 21)) break;   // safety bail-out
                }
                // drain leftover in-flight poll load before any other VMEM;
                // keep v0/v1 alive so the pending write can't clobber a reused reg
                asm volatile("s_waitcnt vmcnt(0)" :: "v"(v0), "v"(v1) : "memory");
            }

            // ---- load A-frags directly from global (2 KB per wave) ----
            const ushort* hs = hbuf + (size_t)((t - 1) & 1) * BATCH * HID
                               + (size_t)(bi * 16 + arow) * HID + w * 256 + kgrp;
            short8 af0, af1, af2, af3, af4, af5, af6, af7;
#define LDA(reg, kk)                                                            \
            asm volatile("global_load_dwordx4 %0, %1, off sc0 sc1"              \
                         : "=v"(reg) : "v"(hs + (kk) * 32) : "memory")
            LDA(af0, 0); LDA(af1, 1); LDA(af2, 2); LDA(af3, 3);
            LDA(af4, 4); LDA(af5, 5); LDA(af6, 6); LDA(af7, 7);
#undef LDA
            asm volatile("s_waitcnt vmcnt(0)" ::: "memory");
            __builtin_amdgcn_sched_barrier(0);

            // ---- 32 MFMAs: 4 n-groups x 8 k-chunks (K-partial accs) ----
            f32x4 a0 = {0,0,0,0}, a1 = {0,0,0,0}, a2 = {0,0,0,0}, a3 = {0,0,0,0};
#define STEP(afk, kk)                                                               \
            a0 = __builtin_amdgcn_mfma_f32_16x16x32_bf16(afk, wf[0][kk], a0, 0, 0, 0); \
            a1 = __builtin_amdgcn_mfma_f32_16x16x32_bf16(afk, wf[1][kk], a1, 0, 0, 0); \
            a2 = __builtin_amdgcn_mfma_f32_16x16x32_bf16(afk, wf[2][kk], a2, 0, 0, 0); \
            a3 = __builtin_amdgcn_mfma_f32_16x16x32_bf16(afk, wf[3][kk], a3, 0, 0, 0)
            STEP(af0, 0); STEP(af1, 1); STEP(af2, 2); STEP(af3, 3);
            STEP(af4, 4); STEP(af5, 5); STEP(af6, 6); STEP(af7, 7);
#undef STEP

            // ---- write K-partials to LDS (C/D map: row=(lane>>4)*4+j, col=arow) ----
#pragma unroll
            for (int j = 0; j < 4; ++j) {
                const int br = (lane >> 4) * 4 + j;
                P[w][br][arow]      = a0[j];
                P[w][br][16 + arow] = a1[j];
                P[w][br][32 + arow] = a2[j];
                P[w][br][48 + arow] = a3[j];
            }
            __syncthreads();

            // ---- reduce 4 wave-partials for (eb, n0..n0+3) ----
            f32x4 r0 = *(const f32x4*)&P[0][eb][n0];
            f32x4 r1 = *(const f32x4*)&P[1][eb][n0];
            f32x4 r2 = *(const f32x4*)&P[2][eb][n0];
            f32x4 r3 = *(const f32x4*)&P[3][eb][n0];
            acc = (r0 + r1) + (r2 + r3);
        }

        // ---- epilogue in (b,n)-contiguous layout ----
        f32x4 hw;
#pragma unroll
        for (int j = 0; j < 4; ++j) {
            float hn = xtv[j] + acc[j] + bias4[j];
            hn       = hn > 0.0f ? hn : 0.0f;
            hw[j]    = hprev[j] * 0.8f + 0.2f * hn;
        }
        hprev = hw;

        // ---- publish 8B bf16 -> per-wave drain -> per-wave flag (no barrier) ----
        uint2 pk;
        pk.x = (uint)f2bf(hw[0]) | ((uint)f2bf(hw[1]) << 16);
        pk.y = (uint)f2bf(hw[2]) | ((uint)f2bf(hw[3]) << 16);
        ushort* hdst = hbuf + (size_t)(t & 1) * BATCH * HID
                       + (size_t)(bi * 16 + eb) * HID + ni * 64 + n0;
        asm volatile("global_store_dwordx2 %0, %1, off sc0 sc1" :: "v"(hdst), "v"(pk) : "memory");
        asm volatile("s_waitcnt vmcnt(0)" ::: "memory");
        if (lane == 0) {
            int one = 1;
            int* fdst = flags + (((size_t)t * 8 + bi) * 64 + ni * 4 + w) * 4;
            asm volatile("global_store_dword %0, %1, off sc0 sc1" :: "v"(fdst), "v"(one) : "memory");
        }

        // ---- off-critical-path: out/hidden stores + next xt prefetch ----
        float* od = out + (size_t)t * BATCH * HID + (size_t)(bi * 16 + eb) * HID + ni * 64 + n0;
        *(f32x4*)od = hw;
        if (t == S_LEN - 1) {
            float* hd = hidden + (size_t)(bi * 16 + eb) * HID + ni * 64 + n0;
            *(f32x4*)hd = hw;
        }
        if (t + 1 < S_LEN)
            xtv = *(const f32x4*)&ip[(size_t)(t + 1) * BATCH * HID
                                     + (size_t)(bi * 16 + eb) * HID + ni * 64 + n0];
    }
}

extern "C" void kernel_launch(void* const* d_in, const int* in_sizes, int n_in,
                              void* d_out, int out_size, void* d_ws, size_t ws_size,
                              hipStream_t stream) {
    const float* x    = (const float*)d_in[0];
    const float* W_in = (const float*)d_in[1];
    const float* b_in = (const float*)d_in[2];
    const float* W_hh = (const float*)d_in[3];
    const float* b_hh = (const float*)d_in[4];

    float* out    = (float*)d_out;
    float* hidden = out + (size_t)S_LEN * BATCH * HID;
    float* ip     = hidden + (size_t)BATCH * HID;

    char* ws = (char*)d_ws;
    ushort* hbuf  = (ushort*)ws;                                // 512 KB h ring
    int*    flags = (int*)(ws + (size_t)1024 * 1024);           // 4 MB wave flags (16B pad)

    hipMemsetAsync(flags, 0, (size_t)S_LEN * 8 * 64 * 4 * sizeof(int), stream);
    ip_gemm<<<(65536 / 64) * (HID / 64), 256, 0, stream>>>(x, W_in, b_in, ip);
    ctrnn_rec<<<128, 256, 0, stream>>>(W_hh, b_hh, ip, out, hidden, hbuf, flags);
}

// Round 10
// 1751.932 us; speedup vs baseline: 1.2759x; 1.2144x over previous
//
#include <hip/hip_runtime.h>
#include <hip/hip_bf16.h>

// CTRNN on MI355X.
//   out layout (fp32): output[512][128][1024] | hidden[128][1024] | ip[512][128][1024]
// Phase 1: ip = x @ W_in^T + b_in  (bf16 MFMA, W_in converted inline, fp32 out)
// Phase 2: persistent recurrent kernel (R6 K-split structure) with SELF-
//          VALIDATING h exchange: h >= 0 always (relu + leaky from h0=0), so the
//          bf16 sign bit carries the ring-generation parity ((t>>1)&1). Producer
//          publishes with NO drain/flag/barrier; consumer polls the data itself
//          (one RTT = detect + deliver), masks sign bits, feeds MFMA directly.
//          Ring init = 0xFF (sign=1) so t=0 data (parity 0) can't false-positive.

typedef __attribute__((ext_vector_type(8))) short short8;
typedef __attribute__((ext_vector_type(4))) float f32x4;
typedef __attribute__((ext_vector_type(4))) uint  uint4v;

#define S_LEN 512
#define BATCH 128
#define IN_DIM 512
#define HID 1024

__device__ __forceinline__ ushort f2bf(float f) {
    __hip_bfloat16 h = __float2bfloat16(f);
    return *reinterpret_cast<ushort*>(&h);
}

// ---------------- input projection GEMM (inline W_in cvt) ----------------
__global__ __launch_bounds__(256) void ip_gemm(const float* __restrict__ x,
                                               const float* __restrict__ W_in,
                                               const float* __restrict__ b_in,
                                               float* __restrict__ ip) {
    __shared__ __align__(16) ushort As[64 * 32];
    __shared__ __align__(16) ushort Bs[64 * 32];
    const int tid  = threadIdx.x;
    const int lane = tid & 63;
    const int w    = tid >> 6;
    const int mt   = blockIdx.x >> 4;
    const int nt   = blockIdx.x & 15;
    const long Mbase = (long)mt * 64;
    const int  Nbase = nt * 64;

    const int sr = tid >> 2;
    const int sk = (tid & 3) * 8;

    f32x4 acc0 = {0,0,0,0}, acc1 = {0,0,0,0}, acc2 = {0,0,0,0}, acc3 = {0,0,0,0};

    const int ar    = w * 16 + (lane & 15);
    const int kb    = ((lane >> 4) * 8) * 2;
    const int aoff  = (ar * 64 + kb) ^ ((ar & 7) << 4);
    const int boff  = ((lane & 15) * 64 + kb) ^ (((lane & 15) & 7) << 4);
    const int soff  = (sr * 64 + sk * 2) ^ ((sr & 7) << 4);

    for (int kc = 0; kc < IN_DIM; kc += 32) {
        const float* ap = x + (Mbase + sr) * IN_DIM + kc + sk;
        f32x4 av0 = *(const f32x4*)ap;
        f32x4 av1 = *(const f32x4*)(ap + 4);
        const float* wp = W_in + (size_t)(Nbase + sr) * IN_DIM + kc + sk;
        f32x4 bv0 = *(const f32x4*)wp;
        f32x4 bv1 = *(const f32x4*)(wp + 4);
        short8 av, bv;
#pragma unroll
        for (int j = 0; j < 4; ++j) {
            av[j]     = (short)f2bf(av0[j]);
            av[4 + j] = (short)f2bf(av1[j]);
            bv[j]     = (short)f2bf(bv0[j]);
            bv[4 + j] = (short)f2bf(bv1[j]);
        }
        __syncthreads();
        *(short8*)((char*)As + soff) = av;
        *(short8*)((char*)Bs + soff) = bv;
        __syncthreads();

        short8 a  = *(const short8*)((char*)As + aoff);
        short8 b0 = *(const short8*)((char*)Bs + boff);
        short8 b1 = *(const short8*)((char*)Bs + boff + 1024);
        short8 b2 = *(const short8*)((char*)Bs + boff + 2048);
        short8 b3 = *(const short8*)((char*)Bs + boff + 3072);
        acc0 = __builtin_amdgcn_mfma_f32_16x16x32_bf16(a, b0, acc0, 0, 0, 0);
        acc1 = __builtin_amdgcn_mfma_f32_16x16x32_bf16(a, b1, acc1, 0, 0, 0);
        acc2 = __builtin_amdgcn_mfma_f32_16x16x32_bf16(a, b2, acc2, 0, 0, 0);
        acc3 = __builtin_amdgcn_mfma_f32_16x16x32_bf16(a, b3, acc3, 0, 0, 0);
    }

    const int nl   = lane & 15;
    const int mrow = w * 16 + (lane >> 4) * 4;
    const float bi0 = b_in[Nbase + nl];
    const float bi1 = b_in[Nbase + 16 + nl];
    const float bi2 = b_in[Nbase + 32 + nl];
    const float bi3 = b_in[Nbase + 48 + nl];
#pragma unroll
    for (int j = 0; j < 4; ++j) {
        float* op = ip + (Mbase + mrow + j) * HID + Nbase + nl;
        op[0]  = acc0[j] + bi0;
        op[16] = acc1[j] + bi1;
        op[32] = acc2[j] + bi2;
        op[48] = acc3[j] + bi3;
    }
}

// ---------------- persistent recurrent kernel ----------------
// grid = 128 blocks: bi = blockIdx&7 (16 batch rows), ni = blockIdx>>3 (64 H cols).
// hbuf: bf16[2][128][1024] ring; sign bit of each element = generation parity.
__global__ __launch_bounds__(256, 1) void ctrnn_rec(const float* __restrict__ whh,
                                                    const float* __restrict__ b_hh,
                                                    const float* __restrict__ ip,
                                                    float* __restrict__ out,
                                                    float* __restrict__ hidden,
                                                    ushort* __restrict__ hbuf) {
    const int tid  = threadIdx.x;
    const int lane = tid & 63;
    const int w    = tid >> 6;
    const int bi   = blockIdx.x & 7;
    const int ni   = blockIdx.x >> 3;

    __shared__ __align__(16) float P[4][16][68];   // 17.4 KB K-partials (padded)

    const int arow = lane & 15;          // A row = batch row; also W col within group
    const int kgrp = (lane >> 4) * 8;    // k sub-offset within 32-chunk

    // W_hh fragments: wf[g][kk] = W[ni*64+g*16+arow][w*256 + kk*32 + kgrp + 0..7]
    short8 wf[4][8];
#pragma unroll
    for (int g = 0; g < 4; ++g)
#pragma unroll
        for (int kk = 0; kk < 8; ++kk) {
            const float* wp = whh + (size_t)(ni * 64 + g * 16 + arow) * HID
                              + w * 256 + kk * 32 + kgrp;
            f32x4 w0 = *(const f32x4*)wp;
            f32x4 w1 = *(const f32x4*)(wp + 4);
            short8 f;
#pragma unroll
            for (int j = 0; j < 4; ++j) {
                f[j]     = (short)f2bf(w0[j]);
                f[4 + j] = (short)f2bf(w1[j]);
            }
            wf[g][kk] = f;
        }

    const int eb = tid >> 4;
    const int n0 = (tid & 15) * 4;
    const f32x4 bias4 = *(const f32x4*)&b_hh[ni * 64 + n0];
    f32x4 hprev = {0, 0, 0, 0};
    f32x4 xtv   = *(const f32x4*)&ip[(size_t)(bi * 16 + eb) * HID + ni * 64 + n0];

    for (int t = 0; t < S_LEN; ++t) {
        f32x4 acc = {0, 0, 0, 0};
        if (t > 0) {
            // ---- self-validating data poll: parity in sign bits ----
            const uint sexp = (((t - 1) >> 1) & 1) ? 0x80008000u : 0u;
            const ushort* hs = hbuf + (size_t)((t - 1) & 1) * BATCH * HID
                               + (size_t)(bi * 16 + arow) * HID + w * 256 + kgrp;
            uint4v h0, h1, h2, h3, h4, h5, h6, h7;
            long spin = 0;
            for (;;) {
#define LDA(reg, kk)                                                            \
                asm volatile("global_load_dwordx4 %0, %1, off sc0 sc1"          \
                             : "=v"(reg) : "v"(hs + (kk) * 32) : "memory")
                LDA(h0, 0); LDA(h1, 1); LDA(h2, 2); LDA(h3, 3);
                LDA(h4, 4); LDA(h5, 5); LDA(h6, 6); LDA(h7, 7);
#undef LDA
                asm volatile("s_waitcnt vmcnt(0)" ::: "memory");
                __builtin_amdgcn_sched_barrier(0);   // rule #18: no hoist above vmcnt
                uint4v o = (h0 ^ sexp) | (h1 ^ sexp) | (h2 ^ sexp) | (h3 ^ sexp)
                         | (h4 ^ sexp) | (h5 ^ sexp) | (h6 ^ sexp) | (h7 ^ sexp);
                uint bad = (o[0] | o[1] | o[2] | o[3]) & 0x80008000u;
                if (__all(bad == 0)) break;
                if (++spin > (1L << 20)) break;   // safety bail-out
            }
            // strip parity bits -> clean bf16 (h >= 0 so sign is spare)
            h0 &= 0x7FFF7FFFu; h1 &= 0x7FFF7FFFu; h2 &= 0x7FFF7FFFu; h3 &= 0x7FFF7FFFu;
            h4 &= 0x7FFF7FFFu; h5 &= 0x7FFF7FFFu; h6 &= 0x7FFF7FFFu; h7 &= 0x7FFF7FFFu;
            __builtin_amdgcn_sched_barrier(0);

            // ---- 32 MFMAs: 4 n-groups x 8 k-chunks (K-partial accs) ----
            f32x4 a0 = {0,0,0,0}, a1 = {0,0,0,0}, a2 = {0,0,0,0}, a3 = {0,0,0,0};
#define STEP(hk, kk)                                                                 \
            a0 = __builtin_amdgcn_mfma_f32_16x16x32_bf16(*(short8*)&hk, wf[0][kk], a0, 0, 0, 0); \
            a1 = __builtin_amdgcn_mfma_f32_16x16x32_bf16(*(short8*)&hk, wf[1][kk], a1, 0, 0, 0); \
            a2 = __builtin_amdgcn_mfma_f32_16x16x32_bf16(*(short8*)&hk, wf[2][kk], a2, 0, 0, 0); \
            a3 = __builtin_amdgcn_mfma_f32_16x16x32_bf16(*(short8*)&hk, wf[3][kk], a3, 0, 0, 0)
            STEP(h0, 0); STEP(h1, 1); STEP(h2, 2); STEP(h3, 3);
            STEP(h4, 4); STEP(h5, 5); STEP(h6, 6); STEP(h7, 7);
#undef STEP

            // ---- write K-partials to LDS (C/D map: row=(lane>>4)*4+j, col=arow) ----
#pragma unroll
            for (int j = 0; j < 4; ++j) {
                const int br = (lane >> 4) * 4 + j;
                P[w][br][arow]      = a0[j];
                P[w][br][16 + arow] = a1[j];
                P[w][br][32 + arow] = a2[j];
                P[w][br][48 + arow] = a3[j];
            }
            __syncthreads();

            // ---- reduce 4 wave-partials for (eb, n0..n0+3) ----
            f32x4 r0 = *(const f32x4*)&P[0][eb][n0];
            f32x4 r1 = *(const f32x4*)&P[1][eb][n0];
            f32x4 r2 = *(const f32x4*)&P[2][eb][n0];
            f32x4 r3 = *(const f32x4*)&P[3][eb][n0];
            acc = (r0 + r1) + (r2 + r3);
        }

        // ---- epilogue in (b,n)-contiguous layout ----
        f32x4 hw;
#pragma unroll
        for (int j = 0; j < 4; ++j) {
            float hn = xtv[j] + acc[j] + bias4[j];
            hn       = hn > 0.0f ? hn : 0.0f;
            hw[j]    = hprev[j] * 0.8f + 0.2f * hn;
        }
        hprev = hw;

        // ---- publish with parity-stamped sign bits: NO drain, NO flag ----
        const uint sbit = ((t >> 1) & 1) ? 0x80008000u : 0u;
        uint2 pk;
        pk.x = ((uint)f2bf(hw[0]) | ((uint)f2bf(hw[1]) << 16)) | sbit;
        pk.y = ((uint)f2bf(hw[2]) | ((uint)f2bf(hw[3]) << 16)) | sbit;
        ushort* hdst = hbuf + (size_t)(t & 1) * BATCH * HID
                       + (size_t)(bi * 16 + eb) * HID + ni * 64 + n0;
        asm volatile("global_store_dwordx2 %0, %1, off sc0 sc1" :: "v"(hdst), "v"(pk) : "memory");

        // WAR barrier: all reduce-reads of this step done before next P-write;
        // placed after publish-issue so it's off the exchange critical path.
        __syncthreads();

        // ---- off-critical-path: out/hidden stores + next xt prefetch ----
        float* od = out + (size_t)t * BATCH * HID + (size_t)(bi * 16 + eb) * HID + ni * 64 + n0;
        *(f32x4*)od = hw;
        if (t == S_LEN - 1) {
            float* hd = hidden + (size_t)(bi * 16 + eb) * HID + ni * 64 + n0;
            *(f32x4*)hd = hw;
        }
        if (t + 1 < S_LEN)
            xtv = *(const f32x4*)&ip[(size_t)(t + 1) * BATCH * HID
                                     + (size_t)(bi * 16 + eb) * HID + ni * 64 + n0];
    }
}

extern "C" void kernel_launch(void* const* d_in, const int* in_sizes, int n_in,
                              void* d_out, int out_size, void* d_ws, size_t ws_size,
                              hipStream_t stream) {
    const float* x    = (const float*)d_in[0];
    const float* W_in = (const float*)d_in[1];
    const float* b_in = (const float*)d_in[2];
    const float* W_hh = (const float*)d_in[3];
    const float* b_hh = (const float*)d_in[4];

    float* out    = (float*)d_out;
    float* hidden = out + (size_t)S_LEN * BATCH * HID;
    float* ip     = hidden + (size_t)BATCH * HID;

    char* ws = (char*)d_ws;
    ushort* hbuf = (ushort*)ws;   // 512 KB h ring (parity-stamped bf16)

    // init ring to sign=1 everywhere: t=0 (parity 0) can never false-positive
    hipMemsetAsync(hbuf, 0xFF, (size_t)2 * BATCH * HID * sizeof(ushort), stream);
    ip_gemm<<<(65536 / 64) * (HID / 64), 256, 0, stream>>>(x, W_in, b_in, ip);
    ctrnn_rec<<<128, 256, 0, stream>>>(W_hh, b_hh, ip, out, hidden, hbuf);
}

// Round 11
// 1674.731 us; speedup vs baseline: 1.3348x; 1.0461x over previous
//
#include <hip/hip_runtime.h>
#include <hip/hip_bf16.h>

// CTRNN on MI355X.
//   out layout (fp32): output[512][128][1024] | hidden[128][1024] | ip[512][128][1024]
// Phase 1: ip = x @ W_in^T + b_in  (bf16 MFMA, 128x64 tile, W_in converted inline)
// Phase 2: persistent recurrent kernel (R10 protocol, proven):
//          128 blocks = 8 batch-tiles x 16 H-tiles; W_hh slice in VGPRs; K-split
//          across 4 waves; h exchanged via depth-2 ring of parity-stamped bf16
//          (sign bit = generation parity; h >= 0 so sign is spare). Producer
//          publishes with NO drain/flag; consumer polls the data itself.
//          NEW: xt prefetch hoisted pre-MFMA (off poll's vmcnt path);
//          P double-buffered -> ONE barrier per step.

typedef __attribute__((ext_vector_type(8))) short short8;
typedef __attribute__((ext_vector_type(4))) float f32x4;
typedef __attribute__((ext_vector_type(4))) uint  uint4v;

#define S_LEN 512
#define BATCH 128
#define IN_DIM 512
#define HID 1024

__device__ __forceinline__ ushort f2bf(float f) {
    __hip_bfloat16 h = __float2bfloat16(f);
    return *reinterpret_cast<ushort*>(&h);
}

// ---------------- input projection GEMM: 128x64 tile ----------------
__global__ __launch_bounds__(256) void ip_gemm(const float* __restrict__ x,
                                               const float* __restrict__ W_in,
                                               const float* __restrict__ b_in,
                                               float* __restrict__ ip) {
    __shared__ __align__(16) ushort As[128 * 32];   // 8 KB
    __shared__ __align__(16) ushort Bs[64 * 32];    // 4 KB
    const int tid  = threadIdx.x;
    const int lane = tid & 63;
    const int w    = tid >> 6;
    const int mt   = blockIdx.x >> 4;   // 512 M-tiles of 128
    const int nt   = blockIdx.x & 15;
    const long Mbase = (long)mt * 128;
    const int  Nbase = nt * 64;

    const int sr = tid >> 2;          // staging row 0..63
    const int sk = (tid & 3) * 8;     // k offset 0/8/16/24

    f32x4 a00={0,0,0,0}, a01={0,0,0,0}, a02={0,0,0,0}, a03={0,0,0,0};
    f32x4 a10={0,0,0,0}, a11={0,0,0,0}, a12={0,0,0,0}, a13={0,0,0,0};

    const int ar0   = w * 32 + (lane & 15);
    const int ar1   = ar0 + 16;
    const int kb    = ((lane >> 4) * 8) * 2;
    const int aoff0 = (ar0 * 64 + kb) ^ ((ar0 & 7) << 4);
    const int aoff1 = (ar1 * 64 + kb) ^ ((ar1 & 7) << 4);   // (ar1&7)==(ar0&7)
    const int boff  = ((lane & 15) * 64 + kb) ^ (((lane & 15) & 7) << 4);
    const int soff0 = (sr * 64 + sk * 2) ^ ((sr & 7) << 4);
    const int soff1 = ((sr + 64) * 64 + sk * 2) ^ ((sr & 7) << 4);  // 64%8==0

    for (int kc = 0; kc < IN_DIM; kc += 32) {
        const float* ap0 = x + (Mbase + sr) * IN_DIM + kc + sk;
        const float* ap1 = ap0 + (size_t)64 * IN_DIM;
        const float* wp  = W_in + (size_t)(Nbase + sr) * IN_DIM + kc + sk;
        f32x4 x0l = ((const f32x4*)ap0)[0], x0h = ((const f32x4*)ap0)[1];
        f32x4 x1l = ((const f32x4*)ap1)[0], x1h = ((const f32x4*)ap1)[1];
        f32x4 bl  = ((const f32x4*)wp)[0],  bh  = ((const f32x4*)wp)[1];
        short8 av0, av1, bv;
#pragma unroll
        for (int j = 0; j < 4; ++j) {
            av0[j]     = (short)f2bf(x0l[j]);
            av0[4 + j] = (short)f2bf(x0h[j]);
            av1[j]     = (short)f2bf(x1l[j]);
            av1[4 + j] = (short)f2bf(x1h[j]);
            bv[j]      = (short)f2bf(bl[j]);
            bv[4 + j]  = (short)f2bf(bh[j]);
        }
        __syncthreads();
        *(short8*)((char*)As + soff0) = av0;
        *(short8*)((char*)As + soff1) = av1;
        *(short8*)((char*)Bs + soff0) = bv;
        __syncthreads();

        short8 A0 = *(const short8*)((char*)As + aoff0);
        short8 A1 = *(const short8*)((char*)As + aoff1);
        short8 B0 = *(const short8*)((char*)Bs + boff);
        short8 B1 = *(const short8*)((char*)Bs + boff + 1024);
        short8 B2 = *(const short8*)((char*)Bs + boff + 2048);
        short8 B3 = *(const short8*)((char*)Bs + boff + 3072);
        a00 = __builtin_amdgcn_mfma_f32_16x16x32_bf16(A0, B0, a00, 0, 0, 0);
        a01 = __builtin_amdgcn_mfma_f32_16x16x32_bf16(A0, B1, a01, 0, 0, 0);
        a02 = __builtin_amdgcn_mfma_f32_16x16x32_bf16(A0, B2, a02, 0, 0, 0);
        a03 = __builtin_amdgcn_mfma_f32_16x16x32_bf16(A0, B3, a03, 0, 0, 0);
        a10 = __builtin_amdgcn_mfma_f32_16x16x32_bf16(A1, B0, a10, 0, 0, 0);
        a11 = __builtin_amdgcn_mfma_f32_16x16x32_bf16(A1, B1, a11, 0, 0, 0);
        a12 = __builtin_amdgcn_mfma_f32_16x16x32_bf16(A1, B2, a12, 0, 0, 0);
        a13 = __builtin_amdgcn_mfma_f32_16x16x32_bf16(A1, B3, a13, 0, 0, 0);
    }

    const int nl   = lane & 15;
    const int mrow = w * 32 + (lane >> 4) * 4;
    const float bi0 = b_in[Nbase + nl];
    const float bi1 = b_in[Nbase + 16 + nl];
    const float bi2 = b_in[Nbase + 32 + nl];
    const float bi3 = b_in[Nbase + 48 + nl];
#pragma unroll
    for (int j = 0; j < 4; ++j) {
        float* op0 = ip + (Mbase + mrow + j) * HID + Nbase + nl;
        op0[0]  = a00[j] + bi0;
        op0[16] = a01[j] + bi1;
        op0[32] = a02[j] + bi2;
        op0[48] = a03[j] + bi3;
        float* op1 = op0 + (size_t)16 * HID;
        op1[0]  = a10[j] + bi0;
        op1[16] = a11[j] + bi1;
        op1[32] = a12[j] + bi2;
        op1[48] = a13[j] + bi3;
    }
}

// ---------------- persistent recurrent kernel ----------------
// grid = 128 blocks: bi = blockIdx&7 (16 batch rows), ni = blockIdx>>3 (64 H cols).
// hbuf: bf16[2][128][1024] ring; sign bit of each element = generation parity.
__global__ __launch_bounds__(256, 1) void ctrnn_rec(const float* __restrict__ whh,
                                                    const float* __restrict__ b_hh,
                                                    const float* __restrict__ ip,
                                                    float* __restrict__ out,
                                                    float* __restrict__ hidden,
                                                    ushort* __restrict__ hbuf) {
    const int tid  = threadIdx.x;
    const int lane = tid & 63;
    const int w    = tid >> 6;
    const int bi   = blockIdx.x & 7;
    const int ni   = blockIdx.x >> 3;

    __shared__ __align__(16) float P[2][4][16][68];   // 34.8 KB double-buffered partials

    const int arow = lane & 15;          // A row = batch row; also W col within group
    const int kgrp = (lane >> 4) * 8;    // k sub-offset within 32-chunk

    // W_hh fragments: wf[g][kk] = W[ni*64+g*16+arow][w*256 + kk*32 + kgrp + 0..7]
    short8 wf[4][8];
#pragma unroll
    for (int g = 0; g < 4; ++g)
#pragma unroll
        for (int kk = 0; kk < 8; ++kk) {
            const float* wp = whh + (size_t)(ni * 64 + g * 16 + arow) * HID
                              + w * 256 + kk * 32 + kgrp;
            f32x4 w0 = *(const f32x4*)wp;
            f32x4 w1 = *(const f32x4*)(wp + 4);
            short8 f;
#pragma unroll
            for (int j = 0; j < 4; ++j) {
                f[j]     = (short)f2bf(w0[j]);
                f[4 + j] = (short)f2bf(w1[j]);
            }
            wf[g][kk] = f;
        }

    const int eb = tid >> 4;
    const int n0 = (tid & 15) * 4;
    const f32x4 bias4 = *(const f32x4*)&b_hh[ni * 64 + n0];
    const float* xbase = ip + (size_t)(bi * 16 + eb) * HID + ni * 64 + n0;
    f32x4 hprev = {0, 0, 0, 0};
    f32x4 xtv     = *(const f32x4*)xbase;   // xt(0)
    f32x4 xt_next = xtv;

    for (int t = 0; t < S_LEN; ++t) {
        f32x4 acc = {0, 0, 0, 0};
        if (t > 0) {
            // ---- self-validating data poll: parity in sign bits ----
            const uint sexp = (((t - 1) >> 1) & 1) ? 0x80008000u : 0u;
            const ushort* hs = hbuf + (size_t)((t - 1) & 1) * BATCH * HID
                               + (size_t)(bi * 16 + arow) * HID + w * 256 + kgrp;
            uint4v h0, h1, h2, h3, h4, h5, h6, h7;
            long spin = 0;
            for (;;) {
#define LDA(reg, kk)                                                            \
                asm volatile("global_load_dwordx4 %0, %1, off sc0 sc1"          \
                             : "=v"(reg) : "v"(hs + (kk) * 32) : "memory")
                LDA(h0, 0); LDA(h1, 1); LDA(h2, 2); LDA(h3, 3);
                LDA(h4, 4); LDA(h5, 5); LDA(h6, 6); LDA(h7, 7);
#undef LDA
                asm volatile("s_waitcnt vmcnt(0)" ::: "memory");
                __builtin_amdgcn_sched_barrier(0);   // rule #18: no hoist above vmcnt
                uint4v o = (h0 ^ sexp) | (h1 ^ sexp) | (h2 ^ sexp) | (h3 ^ sexp)
                         | (h4 ^ sexp) | (h5 ^ sexp) | (h6 ^ sexp) | (h7 ^ sexp);
                uint bad = (o[0] | o[1] | o[2] | o[3]) & 0x80008000u;
                if (__all(bad == 0)) break;
                if (++spin > (1L << 20)) break;   // safety bail-out
            }
            // strip parity bits -> clean bf16 (h >= 0 so sign is spare)
            h0 &= 0x7FFF7FFFu; h1 &= 0x7FFF7FFFu; h2 &= 0x7FFF7FFFu; h3 &= 0x7FFF7FFFu;
            h4 &= 0x7FFF7FFFu; h5 &= 0x7FFF7FFFu; h6 &= 0x7FFF7FFFu; h7 &= 0x7FFF7FFFu;
            __builtin_amdgcn_sched_barrier(0);

            // ---- hoisted xt(t+1) prefetch: hides HBM miss under MFMA+reduce,
            //      keeps it out of next poll's first vmcnt window ----
            if (t + 1 < S_LEN)
                xt_next = *(const f32x4*)(xbase + (size_t)(t + 1) * BATCH * HID);

            // ---- 32 MFMAs: 4 n-groups x 8 k-chunks (K-partial accs) ----
            f32x4 a0 = {0,0,0,0}, a1 = {0,0,0,0}, a2 = {0,0,0,0}, a3 = {0,0,0,0};
#define STEP(hk, kk)                                                                 \
            a0 = __builtin_amdgcn_mfma_f32_16x16x32_bf16(*(short8*)&hk, wf[0][kk], a0, 0, 0, 0); \
            a1 = __builtin_amdgcn_mfma_f32_16x16x32_bf16(*(short8*)&hk, wf[1][kk], a1, 0, 0, 0); \
            a2 = __builtin_amdgcn_mfma_f32_16x16x32_bf16(*(short8*)&hk, wf[2][kk], a2, 0, 0, 0); \
            a3 = __builtin_amdgcn_mfma_f32_16x16x32_bf16(*(short8*)&hk, wf[3][kk], a3, 0, 0, 0)
            STEP(h0, 0); STEP(h1, 1); STEP(h2, 2); STEP(h3, 3);
            STEP(h4, 4); STEP(h5, 5); STEP(h6, 6); STEP(h7, 7);
#undef STEP

            // ---- write K-partials to P[t&1] (C/D map: row=(lane>>4)*4+j, col=arow) ----
            const int cur = t & 1;
#pragma unroll
            for (int j = 0; j < 4; ++j) {
                const int br = (lane >> 4) * 4 + j;
                P[cur][w][br][arow]      = a0[j];
                P[cur][w][br][16 + arow] = a1[j];
                P[cur][w][br][32 + arow] = a2[j];
                P[cur][w][br][48 + arow] = a3[j];
            }
            __syncthreads();   // the ONLY barrier per step (WAR across t via dbuf)

            // ---- reduce 4 wave-partials for (eb, n0..n0+3) ----
            f32x4 r0 = *(const f32x4*)&P[cur][0][eb][n0];
            f32x4 r1 = *(const f32x4*)&P[cur][1][eb][n0];
            f32x4 r2 = *(const f32x4*)&P[cur][2][eb][n0];
            f32x4 r3 = *(const f32x4*)&P[cur][3][eb][n0];
            acc = (r0 + r1) + (r2 + r3);
        } else {
            xt_next = *(const f32x4*)(xbase + (size_t)1 * BATCH * HID);  // xt(1)
        }

        // ---- epilogue in (b,n)-contiguous layout ----
        f32x4 hw;
#pragma unroll
        for (int j = 0; j < 4; ++j) {
            float hn = xtv[j] + acc[j] + bias4[j];
            hn       = hn > 0.0f ? hn : 0.0f;
            hw[j]    = hprev[j] * 0.8f + 0.2f * hn;
        }
        hprev = hw;

        // ---- publish with parity-stamped sign bits: NO drain, NO flag ----
        const uint sbit = ((t >> 1) & 1) ? 0x80008000u : 0u;
        uint2 pk;
        pk.x = ((uint)f2bf(hw[0]) | ((uint)f2bf(hw[1]) << 16)) | sbit;
        pk.y = ((uint)f2bf(hw[2]) | ((uint)f2bf(hw[3]) << 16)) | sbit;
        ushort* hdst = hbuf + (size_t)(t & 1) * BATCH * HID
                       + (size_t)(bi * 16 + eb) * HID + ni * 64 + n0;
        asm volatile("global_store_dwordx2 %0, %1, off sc0 sc1" :: "v"(hdst), "v"(pk) : "memory");

        // ---- off-critical-path: out/hidden stores; rotate xt ----
        float* od = out + (size_t)t * BATCH * HID + (size_t)(bi * 16 + eb) * HID + ni * 64 + n0;
        *(f32x4*)od = hw;
        if (t == S_LEN - 1) {
            float* hd = hidden + (size_t)(bi * 16 + eb) * HID + ni * 64 + n0;
            *(f32x4*)hd = hw;
        }
        xtv = xt_next;
    }
}

extern "C" void kernel_launch(void* const* d_in, const int* in_sizes, int n_in,
                              void* d_out, int out_size, void* d_ws, size_t ws_size,
                              hipStream_t stream) {
    const float* x    = (const float*)d_in[0];
    const float* W_in = (const float*)d_in[1];
    const float* b_in = (const float*)d_in[2];
    const float* W_hh = (const float*)d_in[3];
    const float* b_hh = (const float*)d_in[4];

    float* out    = (float*)d_out;
    float* hidden = out + (size_t)S_LEN * BATCH * HID;
    float* ip     = hidden + (size_t)BATCH * HID;

    char* ws = (char*)d_ws;
    ushort* hbuf = (ushort*)ws;   // 512 KB h ring (parity-stamped bf16)

    // init ring to sign=1 everywhere: t=0 (parity 0) can never false-positive
    hipMemsetAsync(hbuf, 0xFF, (size_t)2 * BATCH * HID * sizeof(ushort), stream);
    ip_gemm<<<(65536 / 128) * (HID / 64), 256, 0, stream>>>(x, W_in, b_in, ip);
    ctrnn_rec<<<128, 256, 0, stream>>>(W_hh, b_hh, ip, out, hidden, hbuf);
}

// Round 13
// 1375.115 us; speedup vs baseline: 1.6256x; 1.2179x over previous
//
#include <hip/hip_runtime.h>
#include <hip/hip_bf16.h>

// CTRNN on MI355X.
//   out layout (fp32): output[512][128][1024] | hidden[128][1024] | ip[512][128][1024]
// Phase 1: ip = x @ W_in^T + b_in  (bf16 MFMA, 128x128 tile, W_in converted inline)
// Phase 2: persistent recurrent kernel (R11 protocol, proven):
//          128 blocks = 8 batch-tiles x 16 H-tiles; W_hh slice in VGPRs; K-split
//          across 4 waves; h exchanged via depth-2 ring of parity-stamped bf16
//          (sign bit = generation parity; h >= 0 so sign is spare). Producer
//          publishes with NO drain/flag; consumer serial-polls the data itself
//          (single bank, vmcnt(0) dominates every use — the only proven-safe
//          asm-load pattern; R12's banked poll corrupted via regalloc copies).
//          xt prefetch issued post-barrier (off every vmcnt window that matters).

typedef __attribute__((ext_vector_type(8))) short short8;
typedef __attribute__((ext_vector_type(4))) float f32x4;
typedef __attribute__((ext_vector_type(4))) uint  uint4v;

#define S_LEN 512
#define BATCH 128
#define IN_DIM 512
#define HID 1024

__device__ __forceinline__ ushort f2bf(float f) {
    __hip_bfloat16 h = __float2bfloat16(f);
    return *reinterpret_cast<ushort*>(&h);
}

// ---------------- input projection GEMM: 128x128 tile ----------------
__global__ __launch_bounds__(256) void ip_gemm(const float* __restrict__ x,
                                               const float* __restrict__ W_in,
                                               const float* __restrict__ b_in,
                                               float* __restrict__ ip) {
    __shared__ __align__(16) ushort As[128 * 32];   // 8 KB
    __shared__ __align__(16) ushort Bs[128 * 32];   // 8 KB
    const int tid  = threadIdx.x;
    const int lane = tid & 63;
    const int w    = tid >> 6;
    const int mt   = blockIdx.x >> 3;   // 512 M-tiles of 128
    const int nt   = blockIdx.x & 7;    // 8 N-tiles of 128
    const long Mbase = (long)mt * 128;
    const int  Nbase = nt * 128;

    const int sr = tid >> 2;          // staging row 0..63
    const int sk = (tid & 3) * 8;     // k offset 0/8/16/24

    f32x4 c00={0,0,0,0},c01={0,0,0,0},c02={0,0,0,0},c03={0,0,0,0};
    f32x4 c04={0,0,0,0},c05={0,0,0,0},c06={0,0,0,0},c07={0,0,0,0};
    f32x4 c10={0,0,0,0},c11={0,0,0,0},c12={0,0,0,0},c13={0,0,0,0};
    f32x4 c14={0,0,0,0},c15={0,0,0,0},c16={0,0,0,0},c17={0,0,0,0};

    const int ar0   = w * 32 + (lane & 15);
    const int ar1   = ar0 + 16;
    const int kb    = (lane >> 4) * 16;                       // k byte offset
    const int aoff0 = (ar0 * 64 + kb) ^ ((ar0 & 7) << 4);
    const int aoff1 = (ar1 * 64 + kb) ^ ((ar1 & 7) << 4);     // (ar1&7)==(ar0&7)
    const int boff  = ((lane & 15) * 64 + kb) ^ (((lane & 15) & 7) << 4);
    const int soff0 = (sr * 64 + sk * 2) ^ ((sr & 7) << 4);
    const int soff1 = soff0 + 4096;                           // rows +64 (64%8==0)

    for (int kc = 0; kc < IN_DIM; kc += 32) {
        const float* ap0 = x + (Mbase + sr) * IN_DIM + kc + sk;
        const float* ap1 = ap0 + (size_t)64 * IN_DIM;
        const float* wp0 = W_in + (size_t)(Nbase + sr) * IN_DIM + kc + sk;
        const float* wp1 = wp0 + (size_t)64 * IN_DIM;
        f32x4 x0l = ((const f32x4*)ap0)[0], x0h = ((const f32x4*)ap0)[1];
        f32x4 x1l = ((const f32x4*)ap1)[0], x1h = ((const f32x4*)ap1)[1];
        f32x4 b0l = ((const f32x4*)wp0)[0], b0h = ((const f32x4*)wp0)[1];
        f32x4 b1l = ((const f32x4*)wp1)[0], b1h = ((const f32x4*)wp1)[1];
        short8 av0, av1, bv0, bv1;
#pragma unroll
        for (int j = 0; j < 4; ++j) {
            av0[j] = (short)f2bf(x0l[j]); av0[4+j] = (short)f2bf(x0h[j]);
            av1[j] = (short)f2bf(x1l[j]); av1[4+j] = (short)f2bf(x1h[j]);
            bv0[j] = (short)f2bf(b0l[j]); bv0[4+j] = (short)f2bf(b0h[j]);
            bv1[j] = (short)f2bf(b1l[j]); bv1[4+j] = (short)f2bf(b1h[j]);
        }
        __syncthreads();
        *(short8*)((char*)As + soff0) = av0;
        *(short8*)((char*)As + soff1) = av1;
        *(short8*)((char*)Bs + soff0) = bv0;
        *(short8*)((char*)Bs + soff1) = bv1;
        __syncthreads();

        short8 A0 = *(const short8*)((char*)As + aoff0);
        short8 A1 = *(const short8*)((char*)As + aoff1);
#define BSTEP(g)                                                                     \
        { short8 Bv = *(const short8*)((char*)Bs + boff + 1024 * (g));               \
          c0##g = __builtin_amdgcn_mfma_f32_16x16x32_bf16(A0, Bv, c0##g, 0, 0, 0);   \
          c1##g = __builtin_amdgcn_mfma_f32_16x16x32_bf16(A1, Bv, c1##g, 0, 0, 0); }
        BSTEP(0); BSTEP(1); BSTEP(2); BSTEP(3);
        BSTEP(4); BSTEP(5); BSTEP(6); BSTEP(7);
#undef BSTEP
    }

    const int nl   = lane & 15;
    const int mrow = w * 32 + (lane >> 4) * 4;
#define EPI(g)                                                                        \
    { const float bi_ = b_in[Nbase + (g) * 16 + nl];                                  \
      _Pragma("unroll")                                                               \
      for (int j = 0; j < 4; ++j) {                                                   \
          float* op0 = ip + (Mbase + mrow + j) * HID + Nbase + (g) * 16 + nl;         \
          op0[0] = c0##g[j] + bi_;                                                    \
          op0[(size_t)16 * HID] = c1##g[j] + bi_;                                     \
      } }
    EPI(0); EPI(1); EPI(2); EPI(3); EPI(4); EPI(5); EPI(6); EPI(7);
#undef EPI
}

// ---------------- persistent recurrent kernel ----------------
// grid = 128 blocks: bi = blockIdx&7 (16 batch rows), ni = blockIdx>>3 (64 H cols).
// hbuf: bf16[2][128][1024] ring; sign bit of each element = generation parity.
__global__ __launch_bounds__(256, 1) void ctrnn_rec(const float* __restrict__ whh,
                                                    const float* __restrict__ b_hh,
                                                    const float* __restrict__ ip,
                                                    float* __restrict__ out,
                                                    float* __restrict__ hidden,
                                                    ushort* __restrict__ hbuf) {
    const int tid  = threadIdx.x;
    const int lane = tid & 63;
    const int w    = tid >> 6;
    const int bi   = blockIdx.x & 7;
    const int ni   = blockIdx.x >> 3;

    __shared__ __align__(16) float P[2][4][16][68];   // 34.8 KB double-buffered partials

    const int arow = lane & 15;          // A row = batch row; also W col within group
    const int kgrp = (lane >> 4) * 8;    // k sub-offset within 32-chunk

    // W_hh fragments: wf[g][kk] = W[ni*64+g*16+arow][w*256 + kk*32 + kgrp + 0..7]
    short8 wf[4][8];
#pragma unroll
    for (int g = 0; g < 4; ++g)
#pragma unroll
        for (int kk = 0; kk < 8; ++kk) {
            const float* wp = whh + (size_t)(ni * 64 + g * 16 + arow) * HID
                              + w * 256 + kk * 32 + kgrp;
            f32x4 w0 = *(const f32x4*)wp;
            f32x4 w1 = *(const f32x4*)(wp + 4);
            short8 f;
#pragma unroll
            for (int j = 0; j < 4; ++j) {
                f[j]     = (short)f2bf(w0[j]);
                f[4 + j] = (short)f2bf(w1[j]);
            }
            wf[g][kk] = f;
        }

    const int eb = tid >> 4;
    const int n0 = (tid & 15) * 4;
    const f32x4 bias4 = *(const f32x4*)&b_hh[ni * 64 + n0];
    const float* xbase = ip + (size_t)(bi * 16 + eb) * HID + ni * 64 + n0;
    f32x4 hprev = {0, 0, 0, 0};
    f32x4 xtv     = *(const f32x4*)xbase;   // xt(0)
    f32x4 xt_next = xtv;

    for (int t = 0; t < S_LEN; ++t) {
        f32x4 acc = {0, 0, 0, 0};
        if (t > 0) {
            // ---- serial self-validating data poll (single bank, vmcnt(0)) ----
            const uint sexp = (((t - 1) >> 1) & 1) ? 0x80008000u : 0u;
            const ushort* hs = hbuf + (size_t)((t - 1) & 1) * BATCH * HID
                               + (size_t)(bi * 16 + arow) * HID + w * 256 + kgrp;
            uint4v h0, h1, h2, h3, h4, h5, h6, h7;
            long spin = 0;
            for (;;) {
#define LDA(reg, kk)                                                            \
                asm volatile("global_load_dwordx4 %0, %1, off sc0 sc1"          \
                             : "=v"(reg) : "v"(hs + (kk) * 32) : "memory")
                LDA(h0, 0); LDA(h1, 1); LDA(h2, 2); LDA(h3, 3);
                LDA(h4, 4); LDA(h5, 5); LDA(h6, 6); LDA(h7, 7);
#undef LDA
                asm volatile("s_waitcnt vmcnt(0)" ::: "memory");
                __builtin_amdgcn_sched_barrier(0);   // rule #18: no hoist above vmcnt
                uint4v o = (h0 ^ sexp) | (h1 ^ sexp) | (h2 ^ sexp) | (h3 ^ sexp)
                         | (h4 ^ sexp) | (h5 ^ sexp) | (h6 ^ sexp) | (h7 ^ sexp);
                uint bad = (o[0] | o[1] | o[2] | o[3]) & 0x80008000u;
                if (__all(bad == 0)) break;
                if (++spin > (1L << 20)) break;   // safety bail-out
            }
            // strip parity bits -> clean bf16 (h >= 0 so sign is spare)
            h0 &= 0x7FFF7FFFu; h1 &= 0x7FFF7FFFu; h2 &= 0x7FFF7FFFu; h3 &= 0x7FFF7FFFu;
            h4 &= 0x7FFF7FFFu; h5 &= 0x7FFF7FFFu; h6 &= 0x7FFF7FFFu; h7 &= 0x7FFF7FFFu;
            __builtin_amdgcn_sched_barrier(0);

            // ---- 32 MFMAs: 4 n-groups x 8 k-chunks (K-partial accs) ----
            f32x4 a0 = {0,0,0,0}, a1 = {0,0,0,0}, a2 = {0,0,0,0}, a3 = {0,0,0,0};
#define STEP(hk, kk)                                                                 \
            a0 = __builtin_amdgcn_mfma_f32_16x16x32_bf16(*(short8*)&hk, wf[0][kk], a0, 0, 0, 0); \
            a1 = __builtin_amdgcn_mfma_f32_16x16x32_bf16(*(short8*)&hk, wf[1][kk], a1, 0, 0, 0); \
            a2 = __builtin_amdgcn_mfma_f32_16x16x32_bf16(*(short8*)&hk, wf[2][kk], a2, 0, 0, 0); \
            a3 = __builtin_amdgcn_mfma_f32_16x16x32_bf16(*(short8*)&hk, wf[3][kk], a3, 0, 0, 0)
            STEP(h0, 0); STEP(h1, 1); STEP(h2, 2); STEP(h3, 3);
            STEP(h4, 4); STEP(h5, 5); STEP(h6, 6); STEP(h7, 7);
#undef STEP

            // ---- write K-partials to P[t&1] (C/D map: row=(lane>>4)*4+j, col=arow) ----
            const int cur = t & 1;
#pragma unroll
            for (int j = 0; j < 4; ++j) {
                const int br = (lane >> 4) * 4 + j;
                P[cur][w][br][arow]      = a0[j];
                P[cur][w][br][16 + arow] = a1[j];
                P[cur][w][br][32 + arow] = a2[j];
                P[cur][w][br][48 + arow] = a3[j];
            }
            __syncthreads();   // the ONLY barrier per step (WAR across t via dbuf)

            // ---- reduce 4 wave-partials for (eb, n0..n0+3) ----
            f32x4 r0 = *(const f32x4*)&P[cur][0][eb][n0];
            f32x4 r1 = *(const f32x4*)&P[cur][1][eb][n0];
            f32x4 r2 = *(const f32x4*)&P[cur][2][eb][n0];
            f32x4 r3 = *(const f32x4*)&P[cur][3][eb][n0];
            acc = (r0 + r1) + (r2 + r3);
        }

        // ---- xt(t+1) prefetch AFTER the barrier: no vmcnt window waits on it;
        //      latency hides under epilogue/publish/next poll's first round ----
        if (t + 1 < S_LEN)
            xt_next = *(const f32x4*)(xbase + (size_t)(t + 1) * BATCH * HID);

        // ---- epilogue in (b,n)-contiguous layout ----
        f32x4 hw;
#pragma unroll
        for (int j = 0; j < 4; ++j) {
            float hn = xtv[j] + acc[j] + bias4[j];
            hn       = hn > 0.0f ? hn : 0.0f;
            hw[j]    = hprev[j] * 0.8f + 0.2f * hn;
        }
        hprev = hw;

        // ---- publish with parity-stamped sign bits: NO drain, NO flag ----
        const uint sbit = ((t >> 1) & 1) ? 0x80008000u : 0u;
        uint2 pk;
        pk.x = ((uint)f2bf(hw[0]) | ((uint)f2bf(hw[1]) << 16)) | sbit;
        pk.y = ((uint)f2bf(hw[2]) | ((uint)f2bf(hw[3]) << 16)) | sbit;
        ushort* hdst = hbuf + (size_t)(t & 1) * BATCH * HID
                       + (size_t)(bi * 16 + eb) * HID + ni * 64 + n0;
        asm volatile("global_store_dwordx2 %0, %1, off sc0 sc1" :: "v"(hdst), "v"(pk) : "memory");

        // ---- off-critical-path: out/hidden stores; rotate xt ----
        float* od = out + (size_t)t * BATCH * HID + (size_t)(bi * 16 + eb) * HID + ni * 64 + n0;
        *(f32x4*)od = hw;
        if (t == S_LEN - 1) {
            float* hd = hidden + (size_t)(bi * 16 + eb) * HID + ni * 64 + n0;
            *(f32x4*)hd = hw;
        }
        xtv = xt_next;
    }
}

extern "C" void kernel_launch(void* const* d_in, const int* in_sizes, int n_in,
                              void* d_out, int out_size, void* d_ws, size_t ws_size,
                              hipStream_t stream) {
    const float* x    = (const float*)d_in[0];
    const float* W_in = (const float*)d_in[1];
    const float* b_in = (const float*)d_in[2];
    const float* W_hh = (const float*)d_in[3];
    const float* b_hh = (const float*)d_in[4];

    float* out    = (float*)d_out;
    float* hidden = out + (size_t)S_LEN * BATCH * HID;
    float* ip     = hidden + (size_t)BATCH * HID;

    char* ws = (char*)d_ws;
    ushort* hbuf = (ushort*)ws;   // 512 KB h ring (parity-stamped bf16)

    // init ring to sign=1 everywhere: t=0 (parity 0) can never false-positive
    hipMemsetAsync(hbuf, 0xFF, (size_t)2 * BATCH * HID * sizeof(ushort), stream);
    ip_gemm<<<(65536 / 128) * (HID / 128), 256, 0, stream>>>(x, W_in, b_in, ip);
    ctrnn_rec<<<128, 256, 0, stream>>>(W_hh, b_hh, ip, out, hidden, hbuf);
}